// Round 1
// 13626.680 us; speedup vs baseline: 1.1773x; 1.1773x over previous
//
#include <hip/hip_runtime.h>
#include <stdint.h>

#define VOCABN 32000
#define EMBEDN 512
#define CTXN   256
#define HIDN   1024
#define BN     4
#define SN     1024
#define MTOT   (BN*SN)   // 4096

typedef __attribute__((ext_vector_type(8))) short short8;
typedef __attribute__((ext_vector_type(4))) float f32x4;
typedef unsigned long long u64;

__device__ __forceinline__ ushort f2bf(float f) {
    uint x = __float_as_uint(f);
    uint r = (x + 0x7FFFu + ((x >> 16) & 1u)) >> 16;   // RNE
    return (ushort)r;
}
__device__ __forceinline__ float bf2f(ushort h) { return __uint_as_float((uint)h << 16); }

// ---------------------------------------------------------------------------
// Kernel 1: X[m][e] = tok_emb[ids[m]][e] + pos_emb[m%1024][e]  (bf16)
// ---------------------------------------------------------------------------
__global__ __launch_bounds__(256) void embed_kernel(
    const int* __restrict__ ids, const float* __restrict__ tok,
    const float* __restrict__ pos, ushort* __restrict__ X)
{
    int i = blockIdx.x * 256 + threadIdx.x;
    int m = i >> 7;
    int e4 = (i & 127) * 4;
    int id = ids[m];
    int tp = m & 1023;
    float4 a = *(const float4*)(tok + (size_t)id * EMBEDN + e4);
    float4 b = *(const float4*)(pos + (size_t)tp * EMBEDN + e4);
    ushort4 r;
    r.x = f2bf(a.x + b.x); r.y = f2bf(a.y + b.y);
    r.z = f2bf(a.z + b.z); r.w = f2bf(a.w + b.w);
    *(ushort4*)(X + (size_t)m * EMBEDN + e4) = r;
}

// ---------------------------------------------------------------------------
// GEMM: C[m][n] = sum_k A[m][k]*B[n][k] + bias[n]
// A: bf16 [M][K], B: f32 [N][ldb], C: f32 [M][N]. 128x128 tile, BK=32.
// ---------------------------------------------------------------------------
__global__ __launch_bounds__(256) void gemm_bt(
    const ushort* __restrict__ A, const float* __restrict__ B,
    const float* __restrict__ bias, float* __restrict__ C,
    int M, int N, int K, int ldb)
{
    __shared__ ushort As[128 * 40];
    __shared__ ushort Bs[128 * 40];

    const int tid = threadIdx.x;
    const int bm = blockIdx.y, bn = blockIdx.x;
    const int wid = tid >> 6, lane = tid & 63;
    const int wm = wid & 1, wn = wid >> 1;
    const int r15 = lane & 15, kq = lane >> 4;

    f32x4 acc[4][4] = {};

    const int row = tid >> 1, seg = (tid & 1) * 16;
    const ushort* asrc = A + (size_t)(bm * 128 + row) * K + seg;
    const float*  bsrc = B + (size_t)(bn * 128 + row) * ldb + seg;
    ushort* adst = &As[row * 40 + seg];
    ushort* bdst = &Bs[row * 40 + seg];

    for (int k0 = 0; k0 < K; k0 += 32) {
        uint4 a0 = *(const uint4*)(asrc + k0);
        uint4 a1 = *(const uint4*)(asrc + k0 + 8);
        float4 f0 = *(const float4*)(bsrc + k0);
        float4 f1 = *(const float4*)(bsrc + k0 + 4);
        float4 f2 = *(const float4*)(bsrc + k0 + 8);
        float4 f3 = *(const float4*)(bsrc + k0 + 12);
        uint4 p0, p1;
        p0.x = (uint)f2bf(f0.x) | ((uint)f2bf(f0.y) << 16);
        p0.y = (uint)f2bf(f0.z) | ((uint)f2bf(f0.w) << 16);
        p0.z = (uint)f2bf(f1.x) | ((uint)f2bf(f1.y) << 16);
        p0.w = (uint)f2bf(f1.z) | ((uint)f2bf(f1.w) << 16);
        p1.x = (uint)f2bf(f2.x) | ((uint)f2bf(f2.y) << 16);
        p1.y = (uint)f2bf(f2.z) | ((uint)f2bf(f2.w) << 16);
        p1.z = (uint)f2bf(f3.x) | ((uint)f2bf(f3.y) << 16);
        p1.w = (uint)f2bf(f3.z) | ((uint)f2bf(f3.w) << 16);
        *(uint4*)adst = a0;
        *(uint4*)(adst + 8) = a1;
        *(uint4*)bdst = p0;
        *(uint4*)(bdst + 8) = p1;
        __syncthreads();

        short8 af[4], bfv[4];
        #pragma unroll
        for (int mt = 0; mt < 4; ++mt)
            af[mt] = *(const short8*)&As[(wm * 64 + mt * 16 + r15) * 40 + kq * 8];
        #pragma unroll
        for (int nt = 0; nt < 4; ++nt)
            bfv[nt] = *(const short8*)&Bs[(wn * 64 + nt * 16 + r15) * 40 + kq * 8];
        #pragma unroll
        for (int mt = 0; mt < 4; ++mt)
            #pragma unroll
            for (int nt = 0; nt < 4; ++nt)
                acc[mt][nt] = __builtin_amdgcn_mfma_f32_16x16x32_bf16(
                    af[mt], bfv[nt], acc[mt][nt], 0, 0, 0);
        __syncthreads();
    }

    #pragma unroll
    for (int mt = 0; mt < 4; ++mt) {
        #pragma unroll
        for (int nt = 0; nt < 4; ++nt) {
            int n = bn * 128 + wn * 64 + nt * 16 + r15;
            float bv = bias[n];
            #pragma unroll
            for (int i = 0; i < 4; ++i) {
                int m = bm * 128 + wm * 64 + mt * 16 + kq * 4 + i;
                C[(size_t)m * N + n] = acc[mt][nt][i] + bv;
            }
        }
    }
}

// ---------------------------------------------------------------------------
// M = W0c * Wc  (f32).  M[i][j] = sum_c W0[i][512+c] * Wc[c][j].
// ---------------------------------------------------------------------------
__global__ __launch_bounds__(256) void mk_kernel(
    const float* __restrict__ W0, const float* __restrict__ Wc,
    float* __restrict__ M)
{
    __shared__ float w0r[4][256];
    const int tid = threadIdx.x;
    const int i0 = blockIdx.x * 4;
    for (int idx = tid; idx < 1024; idx += 256) {
        int r = idx >> 8, c = idx & 255;
        w0r[r][c] = W0[(size_t)(i0 + r) * 768 + 512 + c];
    }
    __syncthreads();
    for (int rep = 0; rep < 4; ++rep) {
        int j = rep * 256 + tid;
        float a0 = 0, a1 = 0, a2 = 0, a3 = 0;
        for (int c = 0; c < 256; ++c) {
            float wv = Wc[(size_t)c * 1024 + j];
            a0 += w0r[0][c] * wv; a1 += w0r[1][c] * wv;
            a2 += w0r[2][c] * wv; a3 += w0r[3][c] * wv;
        }
        M[(size_t)(i0 + 0) * 1024 + j] = a0;
        M[(size_t)(i0 + 1) * 1024 + j] = a1;
        M[(size_t)(i0 + 2) * 1024 + j] = a2;
        M[(size_t)(i0 + 3) * 1024 + j] = a3;
    }
}

// ---------------------------------------------------------------------------
// Recurrence: dataflow-flag sync (no central barrier counter).
// 64 WGs x 256 threads, co-resident (1 WG/CU at 148.7 KB LDS).
// Lane L (<64) owns (batch n = L>>4, row m = L&15) of this WG's 16-row slice.
// Publish format: one uint per h value = hi-bf16 | residual-bf16 << 16.
// Consumer repacks into the same st_hi/st_lo pair-words as before.
// ---------------------------------------------------------------------------
__device__ __forceinline__ void wait_flags(uint* flags, uint target) {
    if (threadIdx.x < 64) {
        uint v;
        do {
            v = __hip_atomic_load(flags + threadIdx.x, __ATOMIC_RELAXED,
                                  __HIP_MEMORY_SCOPE_AGENT);
        } while (__any(v < target));
        __builtin_amdgcn_fence(__ATOMIC_ACQUIRE, "agent");
    }
    __syncthreads();
}

__global__ __launch_bounds__(256) void rec_kernel(
    const float* __restrict__ W0, const float* __restrict__ W1g,
    const float* __restrict__ b1g, const float* __restrict__ bcg,
    const float* __restrict__ Mg,
    uint* pub0, uint* pub1, uint* flag0, uint* flag1,
    const float* __restrict__ u_g, ushort* __restrict__ Hout)
{
    extern __shared__ char smem[];
    ushort* W1f_hi = (ushort*)(smem);            // 32768
    ushort* W1f_lo = (ushort*)(smem + 32768);    // 32768
    ushort* Mf_hi  = (ushort*)(smem + 65536);    // 32768
    ushort* Mf_lo  = (ushort*)(smem + 98304);    // 32768
    uint*   st_hi  = (uint*)(smem + 131072);     // [4][520] = 8320
    uint*   st_lo  = (uint*)(smem + 139392);     // 8320
    float*  red    = (float*)(smem + 147712);    // 1024

    const int wg = blockIdx.x, tid = threadIdx.x;
    const int wv = tid >> 6, lane = tid & 63;

    // one-time: split W1 and M slices into MFMA A-fragment order
    for (int idx = tid; idx < 16384; idx += 256) {
        int j = idx & 7, ln = (idx >> 3) & 63, ks = idx >> 9;
        int m = ln & 15, kq = ln >> 4;
        int k = ks * 32 + kq * 8 + j;
        float w1 = W1g[(size_t)(wg * 16 + m) * 1024 + k];
        ushort h = f2bf(w1);
        W1f_hi[idx] = h;
        W1f_lo[idx] = f2bf(w1 - bf2f(h));
        float mm = Mg[(size_t)(wg * 16 + m) * 1024 + k];
        ushort mh = f2bf(mm);
        Mf_hi[idx] = mh;
        Mf_lo[idx] = f2bf(mm - bf2f(mh));
    }

    float a_reg = 0.f, u_reg = 0.f, b1_reg = 0.f, ds_reg = 0.f;
    if (tid < 64) {
        int m = tid & 15, n = tid >> 4;
        b1_reg = b1g[wg * 16 + m];
        float acc = 0.f;
        for (int c = 0; c < 256; ++c)
            acc += W0[(size_t)(wg * 16 + m) * 768 + 512 + c] * bcg[c];
        ds_reg = acc;                             // d = W0c * bc
        u_reg = u_g[(size_t)(n * 1024 + 0) * 1024 + wg * 16 + m];
    }
    __syncthreads();

    for (int t = 0; t < SN; ++t) {
        const uint tgt = (uint)(t + 1);

        // ---- Phase A (wave 0 only): h0 = relu(u + a), publish ----
        if (tid < 64) {
            int m = tid & 15, n = tid >> 4;
            float x = fmaxf(u_reg + a_reg, 0.f);
            ushort ph = f2bf(x);
            uint w = (uint)ph | ((uint)f2bf(x - bf2f(ph)) << 16);
            __hip_atomic_store(pub0 + n * 1024 + wg * 16 + m, w,
                               __ATOMIC_RELAXED, __HIP_MEMORY_SCOPE_AGENT);
            if (tid == 0)
                __hip_atomic_store(flag0 + wg, tgt,
                                   __ATOMIC_RELEASE, __HIP_MEMORY_SCOPE_AGENT);
        }
        wait_flags(flag0, tgt);

        // ---- Phase B: stage h0, h1 = relu(W1*h0 + b1) ----
        {
            const u64* p64 = (const u64*)pub0;
            #pragma unroll
            for (int idx = tid; idx < 2048; idx += 256) {
                u64 v = __hip_atomic_load(p64 + idx, __ATOMIC_RELAXED,
                                          __HIP_MEMORY_SCOPE_AGENT);
                uint v0 = (uint)v, v1 = (uint)(v >> 32);
                int s = idx >> 9, w = idx & 511;
                st_hi[s * 520 + w] = (v0 & 0xFFFFu) | (v1 << 16);
                st_lo[s * 520 + w] = (v0 >> 16) | (v1 & 0xFFFF0000u);
            }
        }
        __syncthreads();
        {
            f32x4 acc = {0.f, 0.f, 0.f, 0.f};
            int n = lane & 15, kq = lane >> 4, nc = n & 3;
            #pragma unroll
            for (int s8 = 0; s8 < 8; ++s8) {
                int ks = wv * 8 + s8;
                short8 ah = *(const short8*)&W1f_hi[ks * 512 + lane * 8];
                short8 al = *(const short8*)&W1f_lo[ks * 512 + lane * 8];
                union { uint u[4]; short8 v; } bh, bl;
                #pragma unroll
                for (int q = 0; q < 4; ++q) {
                    bh.u[q] = st_hi[nc * 520 + ks * 16 + kq * 4 + q];
                    bl.u[q] = st_lo[nc * 520 + ks * 16 + kq * 4 + q];
                }
                acc = __builtin_amdgcn_mfma_f32_16x16x32_bf16(ah, bh.v, acc, 0, 0, 0);
                acc = __builtin_amdgcn_mfma_f32_16x16x32_bf16(ah, bl.v, acc, 0, 0, 0);
                acc = __builtin_amdgcn_mfma_f32_16x16x32_bf16(al, bh.v, acc, 0, 0, 0);
            }
            if (n < 4) {
                #pragma unroll
                for (int i = 0; i < 4; ++i) {
                    int m = kq * 4 + i;
                    red[((m * 4 + n) << 2) + wv] = acc[i];
                }
            }
        }
        __syncthreads();
        if (tid < 64) {
            int m = tid & 15, n = tid >> 4;
            f32x4 r4 = *(const f32x4*)&red[(m * 4 + n) << 2];
            float h1 = fmaxf(r4[0] + r4[1] + r4[2] + r4[3] + b1_reg, 0.f);
            Hout[(size_t)(n * 1024 + t) * 1024 + wg * 16 + m] = f2bf(h1);
            ushort ph = f2bf(h1);
            uint w = (uint)ph | ((uint)f2bf(h1 - bf2f(ph)) << 16);
            __hip_atomic_store(pub1 + n * 1024 + wg * 16 + m, w,
                               __ATOMIC_RELAXED, __HIP_MEMORY_SCOPE_AGENT);
            if (tid == 0)
                __hip_atomic_store(flag1 + wg, tgt,
                                   __ATOMIC_RELEASE, __HIP_MEMORY_SCOPE_AGENT);
        }
        wait_flags(flag1, tgt);

        // ---- Phase C: stage h1, a += M*h1 + d ----
        {
            const u64* p64 = (const u64*)pub1;
            #pragma unroll
            for (int idx = tid; idx < 2048; idx += 256) {
                u64 v = __hip_atomic_load(p64 + idx, __ATOMIC_RELAXED,
                                          __HIP_MEMORY_SCOPE_AGENT);
                uint v0 = (uint)v, v1 = (uint)(v >> 32);
                int s = idx >> 9, w = idx & 511;
                st_hi[s * 520 + w] = (v0 & 0xFFFFu) | (v1 << 16);
                st_lo[s * 520 + w] = (v0 >> 16) | (v1 & 0xFFFF0000u);
            }
        }
        if (tid < 64) {                        // prefetch next u
            int m = tid & 15, n = tid >> 4;
            int tn = (t < 1023) ? t + 1 : 1023;
            u_reg = u_g[(size_t)(n * 1024 + tn) * 1024 + wg * 16 + m];
        }
        __syncthreads();
        {
            f32x4 acc = {0.f, 0.f, 0.f, 0.f};
            int n = lane & 15, kq = lane >> 4, nc = n & 3;
            #pragma unroll
            for (int s8 = 0; s8 < 8; ++s8) {
                int ks = wv * 8 + s8;
                short8 ah = *(const short8*)&Mf_hi[ks * 512 + lane * 8];
                short8 al = *(const short8*)&Mf_lo[ks * 512 + lane * 8];
                union { uint u[4]; short8 v; } bh, bl;
                #pragma unroll
                for (int q = 0; q < 4; ++q) {
                    bh.u[q] = st_hi[nc * 520 + ks * 16 + kq * 4 + q];
                    bl.u[q] = st_lo[nc * 520 + ks * 16 + kq * 4 + q];
                }
                acc = __builtin_amdgcn_mfma_f32_16x16x32_bf16(ah, bh.v, acc, 0, 0, 0);
                acc = __builtin_amdgcn_mfma_f32_16x16x32_bf16(ah, bl.v, acc, 0, 0, 0);
                acc = __builtin_amdgcn_mfma_f32_16x16x32_bf16(al, bh.v, acc, 0, 0, 0);
            }
            if (n < 4) {
                #pragma unroll
                for (int i = 0; i < 4; ++i) {
                    int m = kq * 4 + i;
                    red[((m * 4 + n) << 2) + wv] = acc[i];
                }
            }
        }
        __syncthreads();
        if (tid < 64) {
            int m = tid & 15, n = tid >> 4;
            f32x4 r4 = *(const f32x4*)&red[(m * 4 + n) << 2];
            a_reg += r4[0] + r4[1] + r4[2] + r4[3] + ds_reg;
        }
        // next phase-A publish by wave 0 is safe: all other WGs proved (via
        // flag1 >= t+1) that their pub0 reads for step t completed.
    }
}

// ---------------------------------------------------------------------------
// Exclusive prefix-sum of P along t -> traj.  P: [B*S][256] f32 (incl. +bc).
// ---------------------------------------------------------------------------
__global__ __launch_bounds__(256) void scan_kernel(
    const float* __restrict__ P, float* __restrict__ traj)
{
    __shared__ float lds[32][257];
    const int b = blockIdx.x, tid = threadIdx.x;
    float carry = 0.f;
    for (int tt = 0; tt < 32; ++tt) {
        int t0 = tt * 32;
        for (int idx = tid; idx < 32 * 256; idx += 256) {
            int i = idx >> 8, c = idx & 255;
            lds[i][c] = P[(size_t)(b * 1024 + t0 + i) * 256 + c];
        }
        __syncthreads();
        #pragma unroll 1
        for (int i = 0; i < 32; ++i) {
            float old = carry;
            carry += lds[i][tid];
            lds[i][tid] = old;
        }
        __syncthreads();
        for (int idx = tid; idx < 32 * 256; idx += 256) {
            int i = idx >> 8, c = idx & 255;
            traj[(size_t)(b * 1024 + t0 + i) * 256 + c] = lds[i][c];
        }
        __syncthreads();
    }
}

// ---------------------------------------------------------------------------
extern "C" void kernel_launch(void* const* d_in, const int* in_sizes, int n_in,
                              void* d_out, int out_size, void* d_ws, size_t ws_size,
                              hipStream_t stream)
{
    const int*   ids  = (const int*)d_in[0];
    const float* tok  = (const float*)d_in[1];
    const float* pos  = (const float*)d_in[2];
    const float* W0   = (const float*)d_in[3];
    const float* b0   = (const float*)d_in[4];
    const float* W1   = (const float*)d_in[5];
    const float* b1   = (const float*)d_in[6];
    const float* Wout = (const float*)d_in[7];
    const float* bout = (const float*)d_in[8];
    const float* Wc   = (const float*)d_in[9];
    const float* bc   = (const float*)d_in[10];
    float* out = (float*)d_out;
    char* ws = (char*)d_ws;

    // workspace layout
    uint*   pub0  = (uint*)(ws + 0);           // 16 KB (4096 uints)
    uint*   pub1  = (uint*)(ws + 16384);       // 16 KB
    uint*   flag0 = (uint*)(ws + 32768);       // 256 B
    uint*   flag1 = (uint*)(ws + 33024);       // 256 B
    float*  Mg   = (float*)(ws + 65536);                         // 4 MB
    float*  u_g  = (float*)(ws + 65536 + 4194304);               // 16 MB
    ushort* Hbuf = (ushort*)(ws + 65536 + 4194304 + 16777216);   // 8 MB
    ushort* Xbuf = (ushort*)(ws + 65536 + 4194304 + 16777216 + 8388608);  // 4 MB
    float*  Pbuf = (float*)(ws + 65536 + 4194304 + 16777216 + 8388608 + 4194304); // 4 MB

    hipMemsetAsync(ws, 0, 36864, stream);      // pub buffers + flags

    hipFuncSetAttribute(reinterpret_cast<const void*>(rec_kernel),
                        hipFuncAttributeMaxDynamicSharedMemorySize, 148736);

    // 1) embeddings -> X (bf16)
    embed_kernel<<<2048, 256, 0, stream>>>(ids, tok, pos, Xbuf);

    // 2) u = X * W0x^T + b0   (M=4096, N=1024, K=512, ldb=768)
    gemm_bt<<<dim3(8, 32), 256, 0, stream>>>(Xbuf, W0, b0, u_g,
                                             MTOT, HIDN, EMBEDN, 768);

    // 3) M = W0c * Wc  (f32)
    mk_kernel<<<256, 256, 0, stream>>>(W0, Wc, Mg);

    // 4) recurrence -> H (bf16)
    rec_kernel<<<64, 256, 148736, stream>>>(W0, W1, b1, bc, Mg,
                                            pub0, pub1, flag0, flag1,
                                            u_g, Hbuf);

    // 5) logits = H * Wout^T + bout  (M=4096, N=32000, K=1024)
    gemm_bt<<<dim3(250, 32), 256, 0, stream>>>(Hbuf, Wout, bout, out,
                                               MTOT, VOCABN, HIDN, HIDN);

    // 6) P = H * Wc^T + bc ; traj = exclusive-prefix-sum_t(P)
    gemm_bt<<<dim3(2, 32), 256, 0, stream>>>(Hbuf, Wc, bc, Pbuf,
                                             MTOT, CTXN, HIDN, HIDN);
    scan_kernel<<<4, 256, 0, stream>>>(Pbuf, out + (size_t)131072000);
}